// Round 17
// baseline (1056.390 us; speedup 1.0000x reference)
//
#include <hip/hip_runtime.h>
#include <hip/hip_bf16.h>
#include <math.h>

#define N_NODES 50000
#define N_EDGES 640000
#define DIM 128
#define NLAYER 3
#define LN_EPS 1e-5f
#define LOG2E 1.44269504088896f
#define NSCAN 49    // ceil(50000/1024)
#define NT64 782    // ceil(50000/64) 64-row tiles per matrix
#define GRIDB 768   // persistent blocks (3/CU, co-resident via launch_bounds+LDS)

#if __has_builtin(__builtin_amdgcn_exp2f)
#define EXP2(x) __builtin_amdgcn_exp2f(x)
#else
#define EXP2(x) exp2f(x)
#endif

typedef __attribute__((ext_vector_type(8))) short bf16x8;
typedef __attribute__((ext_vector_type(4))) float f32x4;
typedef unsigned long long ull;

__device__ inline ushort f2b(float f) {
    __hip_bfloat16 h = __float2bfloat16(f);
    return *reinterpret_cast<ushort*>(&h);
}
__device__ inline float bf_lo(unsigned u) { return __uint_as_float(u << 16); }
__device__ inline float bf_hi(unsigned u) { return __uint_as_float(u & 0xffff0000u); }
__device__ inline float lr(float t) { return fmaf(0.4f, fabsf(t), 0.6f * t); }
__device__ inline unsigned pack2(float a, float b) {
    return (unsigned)f2b(a) | ((unsigned)f2b(b) << 16);
}
__device__ inline int cw_of(int w) { return (w & 15) + 32 * (w >> 4); }

// agent-scope (LLC-coherent, L2-bypass) accessors for inter-phase data
__device__ inline unsigned aload(const unsigned* p) {
    return __hip_atomic_load(p, __ATOMIC_RELAXED, __HIP_MEMORY_SCOPE_AGENT);
}
__device__ inline ull aload64(const ull* p) {
    return __hip_atomic_load(p, __ATOMIC_RELAXED, __HIP_MEMORY_SCOPE_AGENT);
}
__device__ inline void astore(unsigned* p, unsigned v) {
    __hip_atomic_store(p, v, __ATOMIC_RELAXED, __HIP_MEMORY_SCOPE_AGENT);
}
__device__ inline void astore64(ull* p, ull v) {
    __hip_atomic_store(p, v, __ATOMIC_RELAXED, __HIP_MEMORY_SCOPE_AGENT);
}

// DPP-based add of cross-lane neighbor (VALU, no LDS pipe).
template<int CTRL>
__device__ inline float dppadd(float v) {
    int m = __builtin_amdgcn_update_dpp(0, __float_as_int(v), CTRL, 0xF, 0xF, true);
    return v + __int_as_float(m);
}
__device__ inline float reduce16(float v) {
    v = dppadd<0x124>(v);   // row_ror:4
    v = dppadd<0x128>(v);   // row_ror:8
    v = dppadd<0xB1>(v);    // quad_perm [1,0,3,2]
    v = dppadd<0x4E>(v);    // quad_perm [2,3,0,1]
    return v;
}

// grid-wide arrive-wait barrier (all GRIDB blocks co-resident)
__device__ inline void gridbar(int* cnt, int* gen, int t) {
    __threadfence();            // drain this wave's stores (vmcnt) device-wide
    __syncthreads();
    if (t == 0) {
        int g = __hip_atomic_load(gen, __ATOMIC_RELAXED, __HIP_MEMORY_SCOPE_AGENT);
        int v = __hip_atomic_fetch_add(cnt, 1, __ATOMIC_ACQ_REL, __HIP_MEMORY_SCOPE_AGENT);
        if (v == GRIDB - 1) {
            __hip_atomic_store(cnt, 0, __ATOMIC_RELAXED, __HIP_MEMORY_SCOPE_AGENT);
            __hip_atomic_store(gen, g + 1, __ATOMIC_RELEASE, __HIP_MEMORY_SCOPE_AGENT);
        } else {
            while (__hip_atomic_load(gen, __ATOMIC_ACQUIRE, __HIP_MEMORY_SCOPE_AGENT) == g)
                __builtin_amdgcn_s_sleep(8);
        }
    }
    __syncthreads();
}

// ---------------- zero-fill ----------------

__global__ __launch_bounds__(256) void zerofill(int4* __restrict__ p, int n4) {
    int i = blockIdx.x * 256 + threadIdx.x;
    if (i < n4) p[i] = make_int4(0, 0, 0, 0);
}

// ---------------- fused init: curb pack + Wt convert(k-perm) + deg hist + params ----

__global__ __launch_bounds__(256) void fusedinit(
    const float* __restrict__ x, unsigned* __restrict__ curb,
    const float* __restrict__ Wl, const float* __restrict__ Wr, ushort* __restrict__ Wt,
    const int* __restrict__ dst, int* __restrict__ deg,
    const float* __restrict__ att, const float* __restrict__ bias,
    const float* __restrict__ gamma, const float* __restrict__ beta,
    float2* __restrict__ params)
{
    int b = blockIdx.x, t = threadIdx.x;
    if (b < 12500) {
        int i = b * 256 + t;                 // i < N*64
        int node = i >> 6, w = i & 63;
        int c = cw_of(w);
        curb[i] = pack2(x[node * DIM + c], x[node * DIM + c + 16]);
    } else if (b < 12884) {
        int i = (b - 12500) * 256 + t;
        if (i < NLAYER * 2 * DIM * DIM) {
            int p = i & 127, n = (i >> 7) & 127, mat = (i >> 14) & 1, l = i >> 15;
            int c = cw_of(p >> 1) + (p & 1) * 16;
            const float* W = mat ? Wr : Wl;
            Wt[i] = f2b(W[l * DIM * DIM + c * DIM + n]);
        }
    } else if (b < 15384) {
        int e = (b - 12884) * 256 + t;       // e < 640000 exactly
        atomicAdd(&deg[dst[e]], 1);
    } else {
        int i = t;
        if (i < NLAYER * 64) {
            int l = i >> 6, w = i & 63;
            int c = cw_of(w);
            const float* A = att + l * DIM;
            const float* B = bias + l * DIM;
            const float* G = gamma + l * DIM;
            const float* E = beta + l * DIM;
            params[l * 256 + w]       = make_float2(A[c] * LOG2E, A[c + 16] * LOG2E);
            params[l * 256 + 64 + w]  = make_float2(B[c], B[c + 16]);
            params[l * 256 + 128 + w] = make_float2(G[c], G[c + 16]);
            params[l * 256 + 192 + w] = make_float2(E[c], E[c + 16]);
        }
    }
}

// ---------------- CSR build + contention-free counting sort ----------------

__global__ __launch_bounds__(1024) void scan1(const int* __restrict__ deg,
                                              int* __restrict__ rowptr,
                                              int* __restrict__ bsum,
                                              int* __restrict__ blockhist) {
    __shared__ int sd[1024];
    __shared__ int lh[256];
    int t = threadIdx.x;
    int idx = blockIdx.x * 1024 + t;
    if (t < 256) lh[t] = 0;
    __syncthreads();
    int v = (idx < N_NODES) ? deg[idx] : 0;
    if (idx < N_NODES) atomicAdd(&lh[v < 255 ? v : 255], 1);
    sd[t] = v;
    __syncthreads();
    for (int off = 1; off < 1024; off <<= 1) {
        int add = (t >= off) ? sd[t - off] : 0;
        __syncthreads();
        sd[t] += add;
        __syncthreads();
    }
    if (idx < N_NODES) rowptr[idx + 1] = sd[t];
    if (t == 1023) bsum[blockIdx.x] = sd[1023];
    if (t < 256) blockhist[blockIdx.x * 256 + t] = lh[t];
}

__global__ __launch_bounds__(1024) void midscan(const int* __restrict__ bsum,
                                                int* __restrict__ bcarry,
                                                const int* __restrict__ blockhist,
                                                int* __restrict__ bboff) {
    __shared__ int sh[256];
    int t = threadIdx.x;
    if (t < 256) {
        int tot = 0;
        for (int b = 0; b < NSCAN; ++b) tot += blockhist[b * 256 + t];
        sh[t] = tot;
    }
    __syncthreads();
    for (int off = 1; off < 256; off <<= 1) {
        int add = 0;
        if (t < 256 && t >= off) add = sh[t - off];
        __syncthreads();
        if (t < 256) sh[t] += add;
        __syncthreads();
    }
    if (t < 256) {
        int run = sh[255] - sh[t];          // heavy-first
        for (int b = 0; b < NSCAN; ++b) {
            bboff[b * 256 + t] = run;
            run += blockhist[b * 256 + t];
        }
    }
    if (t == 0) {
        int c = 0;
        for (int b = 0; b < NSCAN; ++b) { bcarry[b] = c; c += bsum[b]; }
    }
}

__global__ __launch_bounds__(1024) void scan2(int* __restrict__ rowptr,
                                              const int* __restrict__ bcarry,
                                              const int* __restrict__ deg,
                                              const int* __restrict__ bboff,
                                              int* __restrict__ order) {
    __shared__ int lh[256];
    int t = threadIdx.x;
    int idx = blockIdx.x * 1024 + t;
    if (t < 256) lh[t] = 0;
    __syncthreads();
    int carry = bcarry[blockIdx.x];
    if (idx == 0) rowptr[0] = 0;
    if (idx < N_NODES) {
        rowptr[idx + 1] += carry;
        int d = deg[idx];
        int bin = d < 255 ? d : 255;
        int rank = atomicAdd(&lh[bin], 1);
        order[bboff[blockIdx.x * 256 + bin] + rank] = idx;
    }
}

// esrc: BYTE offsets (src*256); slotinfo[slot] = (node, e0, e1).
__global__ void scatter_kernel(const int* __restrict__ src, const int* __restrict__ dst,
                               const int* __restrict__ rowptr, int* __restrict__ cnt,
                               int* __restrict__ esrc,
                               const int* __restrict__ order, const int* __restrict__ deg,
                               int4* __restrict__ slotinfo) {
    int e = blockIdx.x * blockDim.x + threadIdx.x;
    if (e < N_EDGES) {
        int d = dst[e];
        int pos = rowptr[d] + atomicAdd(&cnt[d], 1);
        esrc[pos] = src[e] << 8;
    }
    if (e < N_NODES) {
        int nd = order[e];
        int r0 = rowptr[nd];
        slotinfo[e] = make_int4(nd, r0, r0 + deg[nd], 0);
    }
}

// ---------------- agg helpers (agent-scope gathers) ----------------

__device__ inline void gather8(const char* __restrict__ xb, int laneoff,
                               const int j[8], unsigned u[8]) {
    #pragma unroll
    for (int i = 0; i < 8; ++i)
        u[i] = aload((const unsigned*)(xb + j[i] + laneoff));
}

__device__ inline void compute8(const unsigned u[8], float ax, float ay,
                                float xrx, float xry,
                                float& s, float& ox, float& oy) {
    #pragma unroll
    for (int i = 0; i < 8; ++i) {
        float vx = bf_lo(u[i]), vy = bf_hi(u[i]);
        float p = lr(vx + xrx) * ax + lr(vy + xry) * ay;
        p = reduce16(p);
        float w = EXP2(p);
        s += w; ox = fmaf(w, vx, ox); oy = fmaf(w, vy, oy);
    }
}

__device__ inline void computeT(const unsigned u[8], float ax, float ay,
                                float xrx, float xry,
                                float& s, float& ox, float& oy, int rem) {
    #pragma unroll
    for (int i = 0; i < 8; ++i) {
        if (i < rem) {
            float vx = bf_lo(u[i]), vy = bf_hi(u[i]);
            float p = lr(vx + xrx) * ax + lr(vy + xry) * ay;
            p = reduce16(p);
            float w = EXP2(p);
            s += w; ox = fmaf(w, vx, ox); oy = fmaf(w, vy, oy);
        }
    }
}

// ---------------- the fused 3-layer persistent kernel ----------------

__global__ __launch_bounds__(256, 3) void fused_layers(
    const ushort* __restrict__ Wt, const float* __restrict__ blv,
    const float* __restrict__ brv,
    unsigned* __restrict__ curb, unsigned* __restrict__ xlb, unsigned* __restrict__ xrb,
    const int* __restrict__ esrc, const int4* __restrict__ slotinfo,
    const float2* __restrict__ params, float* __restrict__ outf,
    int* __restrict__ barcnt, int* __restrict__ bargen)
{
    __shared__ char ldsB[32768];
    __shared__ char ldsA[16384];
    int t = threadIdx.x;
    int wid = t >> 6, lane = t & 63;
    int wr = wid >> 1, wc = wid & 1;
    int fr = lane & 15, kg = lane >> 4;

    for (int l = 0; l < NLAYER; ++l) {
        // ================= GEMM phase =================
        const ushort* Wt_l = Wt + (size_t)l * 2 * DIM * DIM;
        for (int b = blockIdx.x; b < 2 * NT64; b += GRIDB) {
            int mat = b & 1;
            int tile = b >> 1;
            int rowbase = tile * 64;
            const ushort* W = Wt_l + (size_t)mat * DIM * DIM;

            // stage B (32KB, cached normal loads) and A (16KB, agent loads)
            const char* Bb = (const char*)W;
            #pragma unroll
            for (int i = 0; i < 8; ++i) {
                int o = (i * 256 + t) * 16;
                int row = o >> 8, ch = (o >> 4) & 15;
                *(uint4*)&ldsB[row * 256 + ((ch ^ (row & 7)) << 4)] = *(const uint4*)(Bb + o);
            }
            const ull* Ab = (const ull*)((const char*)curb + (size_t)rowbase * 256);
            #pragma unroll
            for (int i = 0; i < 4; ++i) {
                int o = (i * 256 + t) * 2;           // ull index
                ull v0 = aload64(Ab + o), v1 = aload64(Ab + o + 1);
                int bo = (i * 256 + t) * 16;
                int row = bo >> 8, ch = (bo >> 4) & 15;
                char* dst8 = &ldsA[row * 256 + ((ch ^ (row & 7)) << 4)];
                *(ull*)dst8 = v0; *(ull*)(dst8 + 8) = v1;
            }
            __syncthreads();

            f32x4 acc[2][4];
            #pragma unroll
            for (int mf = 0; mf < 2; ++mf)
                #pragma unroll
                for (int nf = 0; nf < 4; ++nf)
                    acc[mf][nf] = (f32x4){0.f, 0.f, 0.f, 0.f};

            #pragma unroll
            for (int kf = 0; kf < 4; ++kf) {
                int c = kf * 4 + kg;
                bf16x8 af[2], bfr[4];
                #pragma unroll
                for (int mf = 0; mf < 2; ++mf) {
                    int rl = wr * 32 + mf * 16 + fr;
                    af[mf] = *(const bf16x8*)&ldsA[rl * 256 + ((c ^ (rl & 7)) << 4)];
                }
                #pragma unroll
                for (int nf = 0; nf < 4; ++nf) {
                    int nl = wc * 64 + nf * 16 + fr;
                    bfr[nf] = *(const bf16x8*)&ldsB[nl * 256 + ((c ^ (nl & 7)) << 4)];
                }
                #pragma unroll
                for (int mf = 0; mf < 2; ++mf)
                    #pragma unroll
                    for (int nf = 0; nf < 4; ++nf)
                        acc[mf][nf] = __builtin_amdgcn_mfma_f32_16x16x32_bf16(
                            af[mf], bfr[nf], acc[mf][nf], 0, 0, 0);
            }
            __syncthreads();    // done reading ldsA -> reuse as output tile

            const float* bias = (mat ? brv : blv) + l * DIM;
            float bb[4];
            #pragma unroll
            for (int nf = 0; nf < 4; ++nf) bb[nf] = bias[wc * 64 + nf * 16 + fr];

            unsigned* ldsO = (unsigned*)ldsA;
            #pragma unroll
            for (int mf = 0; mf < 2; ++mf) {
                #pragma unroll
                for (int pj = 0; pj < 2; ++pj) {
                    int w = fr + 32 * wc + 16 * pj;
                    #pragma unroll
                    for (int r = 0; r < 4; ++r) {
                        int rl = wr * 32 + mf * 16 + kg * 4 + r;
                        ldsO[rl * 64 + w] =
                            pack2(acc[mf][2 * pj][r] + bb[2 * pj],
                                  acc[mf][2 * pj + 1][r] + bb[2 * pj + 1]);
                    }
                }
            }
            __syncthreads();

            unsigned* out = mat ? xrb : xlb;
            char* ob = (char*)out + (size_t)rowbase * 256;
            #pragma unroll
            for (int i = 0; i < 4; ++i) {
                int o = (i * 256 + t) * 16;
                int row = rowbase + (o >> 8);
                if (row < N_NODES) {
                    ull v0 = *(ull*)&ldsA[o], v1 = *(ull*)&ldsA[o + 8];
                    astore64((ull*)(ob + o), v0);
                    astore64((ull*)(ob + o + 8), v1);
                }
            }
            __syncthreads();
        }
        gridbar(barcnt, bargen, t);

        // ================= AGG phase =================
        const float2* P4 = params + (size_t)l * 256;
        int last = (l == NLAYER - 1);
        for (int sbase = blockIdx.x; sbase < 12500; sbase += GRIDB) {
            int slot = sbase * 4 + wid;
            int4 si = slotinfo[slot];
            int node = __builtin_amdgcn_readfirstlane(si.x);
            int e0   = __builtin_amdgcn_readfirstlane(si.y);
            int e1   = __builtin_amdgcn_readfirstlane(si.z);

            unsigned xru = aload(&xrb[node * 64 + lane]);
            float2 att2 = P4[lane];
            float2 b2   = P4[64 + lane];
            float2 g2   = P4[128 + lane];
            float2 be2  = P4[192 + lane];
            unsigned old = aload(&curb[node * 64 + lane]);
            float xrx = bf_lo(xru), xry = bf_hi(xru);

            const char* xb = (const char*)xlb;
            int laneoff = lane << 2;

            float s = 0.f, ox = 0.f, oy = 0.f;
            int nb = (e1 - e0) >> 3;
            int rem = (e1 - e0) & 7;

            int jc[8], jn[8];
            unsigned uc[8], un[8];

            if (nb > 0) {
                #pragma unroll
                for (int i = 0; i < 8; ++i) jc[i] = esrc[e0 + i];
                gather8(xb, laneoff, jc, uc);
            }
            int ec = e0;
            for (int b2i = 1; b2i < nb; ++b2i) {
                int en = ec + 8;
                #pragma unroll
                for (int i = 0; i < 8; ++i) jn[i] = esrc[en + i];
                gather8(xb, laneoff, jn, un);
                compute8(uc, att2.x, att2.y, xrx, xry, s, ox, oy);
                #pragma unroll
                for (int i = 0; i < 8; ++i) uc[i] = un[i];
                ec = en;
            }
            if (nb > 0) {
                if (rem) {
                    int et = ec + 8;
                    #pragma unroll
                    for (int i = 0; i < 8; ++i)
                        jn[i] = esrc[et + (i < rem ? i : rem - 1)];
                    gather8(xb, laneoff, jn, un);
                    compute8(uc, att2.x, att2.y, xrx, xry, s, ox, oy);
                    computeT(un, att2.x, att2.y, xrx, xry, s, ox, oy, rem);
                } else {
                    compute8(uc, att2.x, att2.y, xrx, xry, s, ox, oy);
                }
            } else if (rem) {
                #pragma unroll
                for (int i = 0; i < 8; ++i)
                    jc[i] = esrc[e0 + (i < rem ? i : rem - 1)];
                gather8(xb, laneoff, jc, uc);
                computeT(uc, att2.x, att2.y, xrx, xry, s, ox, oy, rem);
            }

            float inv = 1.f / (s + 1e-16f);
            float gx = fmaxf(fmaf(ox, inv, b2.x), 0.f);
            float gy = fmaxf(fmaf(oy, inv, b2.y), 0.f);

            float sum = gx + gy;
            sum = reduce16(sum);
            sum += __shfl_xor(sum, 16);
            sum += __shfl_xor(sum, 32);
            float mu = sum * (1.f / 128.f);
            float dx = gx - mu, dy = gy - mu;
            float ss = dx * dx + dy * dy;
            ss = reduce16(ss);
            ss += __shfl_xor(ss, 16);
            ss += __shfl_xor(ss, 32);
            float rstd = rsqrtf(ss * (1.f / 128.f) + LN_EPS);

            float yx = fmaf(dx * rstd, g2.x, be2.x) + bf_lo(old);
            float yy = fmaf(dy * rstd, g2.y, be2.y) + bf_hi(old);

            if (last) {
                int c = cw_of(lane);
                outf[node * DIM + c] = yx;
                outf[node * DIM + c + 16] = yy;
            } else {
                astore(&curb[node * 64 + lane], pack2(yx, yy));
            }
        }
        if (l < NLAYER - 1) gridbar(barcnt, bargen, t);
    }
}

// ---------------- launch ----------------

extern "C" void kernel_launch(void* const* d_in, const int* in_sizes, int n_in,
                              void* d_out, int out_size, void* d_ws, size_t ws_size,
                              hipStream_t stream) {
    const float* x     = (const float*)d_in[0];
    const int*   ei    = (const int*)d_in[1];
    const float* Wl    = (const float*)d_in[2];
    const float* bl    = (const float*)d_in[3];
    const float* Wr    = (const float*)d_in[4];
    const float* br    = (const float*)d_in[5];
    const float* att   = (const float*)d_in[6];
    const float* bias  = (const float*)d_in[7];
    const float* gamma = (const float*)d_in[8];
    const float* beta  = (const float*)d_in[9];
    float* outf = (float*)d_out;

    char* ws = (char*)d_ws;
    size_t off = 0;
    auto alloc = [&](size_t bytes) -> void* {
        void* p = ws + off;
        off += (bytes + 255) & ~size_t(255);
        return p;
    };
    unsigned* curb = (unsigned*)alloc((size_t)N_NODES * 64 * 4 + 16384);  // +tail slack
    unsigned* xlb  = (unsigned*)alloc((size_t)N_NODES * 64 * 4 + 16384);
    unsigned* xrb  = (unsigned*)alloc((size_t)N_NODES * 64 * 4 + 16384);
    ushort* Wt     = (ushort*)alloc((size_t)NLAYER * 2 * DIM * DIM * 2);
    int* esrc      = (int*)alloc((size_t)N_EDGES * 4);
    int* rowptr    = (int*)alloc((size_t)(N_NODES + 1) * 4);
    // contiguous zero region: deg, cnt, bsum, bcarry, barcnt/bargen
    int* zbase     = (int*)alloc((size_t)(2 * N_NODES + 2 * 64 + 64) * 4);
    int* deg = zbase, *cnt = zbase + N_NODES;
    int* bsum = cnt + N_NODES, *bcarry = bsum + 64;
    int* barcnt = bcarry + 64, *bargen = barcnt + 1;
    int* blockhist = (int*)alloc((size_t)NSCAN * 256 * 4);
    int* bboff     = (int*)alloc((size_t)NSCAN * 256 * 4);
    int* order     = (int*)alloc((size_t)N_NODES * 4);
    int4* slotinfo = (int4*)alloc((size_t)N_NODES * 16);
    float2* params = (float2*)alloc((size_t)NLAYER * 256 * sizeof(float2));

    const int* srcArr = ei;
    const int* dstArr = ei + N_EDGES;

    int n4 = (2 * N_NODES + 2 * 64 + 64) / 4;
    zerofill<<<(n4 + 255) / 256, 256, 0, stream>>>((int4*)zbase, n4);
    fusedinit<<<15385, 256, 0, stream>>>(x, curb, Wl, Wr, Wt, dstArr, deg,
                                         att, bias, gamma, beta, params);
    scan1<<<NSCAN, 1024, 0, stream>>>(deg, rowptr, bsum, blockhist);
    midscan<<<1, 1024, 0, stream>>>(bsum, bcarry, blockhist, bboff);
    scan2<<<NSCAN, 1024, 0, stream>>>(rowptr, bcarry, deg, bboff, order);
    scatter_kernel<<<(N_EDGES + 255) / 256, 256, 0, stream>>>(
        srcArr, dstArr, rowptr, cnt, esrc, order, deg, slotinfo);

    fused_layers<<<GRIDB, 256, 0, stream>>>(
        Wt, bl, br, curb, xlb, xrb, esrc, slotinfo, params, outf, barcnt, bargen);
}

// Round 18
// 252.448 us; speedup vs baseline: 4.1846x; 4.1846x over previous
//
#include <hip/hip_runtime.h>
#include <hip/hip_bf16.h>
#include <math.h>

#define N_NODES 50000
#define N_EDGES 640000
#define DIM 128
#define NLAYER 3
#define LN_EPS 1e-5f
#define LOG2E 1.44269504088896f
#define NSCAN 49    // ceil(50000/1024)
#define NT64 782    // ceil(50000/64) 64-row tiles per matrix
#define SCATB 2500  // scatter blocks (640000/256)

#if __has_builtin(__builtin_amdgcn_exp2f)
#define EXP2(x) __builtin_amdgcn_exp2f(x)
#else
#define EXP2(x) exp2f(x)
#endif

typedef __attribute__((ext_vector_type(8))) short bf16x8;
typedef __attribute__((ext_vector_type(4))) float f32x4;
typedef __attribute__((ext_vector_type(4))) unsigned uint4v;

__device__ inline ushort f2b(float f) {
    __hip_bfloat16 h = __float2bfloat16(f);
    return *reinterpret_cast<ushort*>(&h);
}
__device__ inline float bf_lo(unsigned u) { return __uint_as_float(u << 16); }
__device__ inline float bf_hi(unsigned u) { return __uint_as_float(u & 0xffff0000u); }
// leaky_relu(t) = 0.6t + 0.4|t|  (NEG_SLOPE=0.2)
__device__ inline float lr(float t) { return fmaf(0.4f, fabsf(t), 0.6f * t); }
__device__ inline unsigned pack2(float a, float b) {
    return (unsigned)f2b(a) | ((unsigned)f2b(b) << 16);
}
// packed word w of a node row holds channels (cw, cw+16); both in same head.
__device__ inline int cw_of(int w) { return (w & 15) + 32 * (w >> 4); }

// non-temporal stores: write-through toward LLC, leave no dirty L2 state
__device__ inline void nts(unsigned* p, unsigned v) { __builtin_nontemporal_store(v, p); }
__device__ inline void ntsf(float* p, float v) { __builtin_nontemporal_store(v, p); }
__device__ inline void nts4(void* p, uint4v v) {
    __builtin_nontemporal_store(v, (uint4v*)p);
}
__device__ inline void ntsi(int* p, int v) { __builtin_nontemporal_store(v, p); }
__device__ inline void ntsu16(ushort* p, ushort v) { __builtin_nontemporal_store(v, p); }

// DPP-based add of cross-lane neighbor (VALU, no LDS pipe).
template<int CTRL>
__device__ inline float dppadd(float v) {
    int m = __builtin_amdgcn_update_dpp(0, __float_as_int(v), CTRL, 0xF, 0xF, true);
    return v + __int_as_float(m);
}
// sum over each 16-lane group
__device__ inline float reduce16(float v) {
    v = dppadd<0x124>(v);   // row_ror:4
    v = dppadd<0x128>(v);   // row_ror:8
    v = dppadd<0xB1>(v);    // quad_perm [1,0,3,2]
    v = dppadd<0x4E>(v);    // quad_perm [2,3,0,1]
    return v;
}

// ---------------- zero-fill ----------------

__global__ __launch_bounds__(256) void zerofill(uint4v* __restrict__ p, int n4) {
    int i = blockIdx.x * 256 + threadIdx.x;
    if (i < n4) nts4(p + i, (uint4v){0u, 0u, 0u, 0u});
}

// ---------------- fused init: curb pack + Wt convert(k-perm) + deg hist + params ----

__global__ __launch_bounds__(256) void fusedinit(
    const float* __restrict__ x, unsigned* __restrict__ curb,
    const float* __restrict__ Wl, const float* __restrict__ Wr, ushort* __restrict__ Wt,
    const int* __restrict__ dst, int* __restrict__ deg,
    const float* __restrict__ att, const float* __restrict__ bias,
    const float* __restrict__ gamma, const float* __restrict__ beta,
    float2* __restrict__ params)
{
    int b = blockIdx.x, t = threadIdx.x;
    if (b < 12500) {
        int i = b * 256 + t;                 // i < N*64
        int node = i >> 6, w = i & 63;
        int c = cw_of(w);
        nts(&curb[i], pack2(x[node * DIM + c], x[node * DIM + c + 16]));
    } else if (b < 12884) {
        int i = (b - 12500) * 256 + t;
        if (i < NLAYER * 2 * DIM * DIM) {
            int p = i & 127, n = (i >> 7) & 127, mat = (i >> 14) & 1, l = i >> 15;
            int c = cw_of(p >> 1) + (p & 1) * 16;
            const float* W = mat ? Wr : Wl;
            ntsu16(&Wt[i], f2b(W[l * DIM * DIM + c * DIM + n]));
        }
    } else if (b < 15384) {
        int e = (b - 12884) * 256 + t;       // e < 640000 exactly
        atomicAdd(&deg[dst[e]], 1);
    } else {
        int i = t;
        if (i < NLAYER * 64) {
            int l = i >> 6, w = i & 63;
            int c = cw_of(w);
            const float* A = att + l * DIM;
            const float* B = bias + l * DIM;
            const float* G = gamma + l * DIM;
            const float* E = beta + l * DIM;
            params[l * 256 + w]       = make_float2(A[c] * LOG2E, A[c + 16] * LOG2E);
            params[l * 256 + 64 + w]  = make_float2(B[c], B[c + 16]);
            params[l * 256 + 128 + w] = make_float2(G[c], G[c + 16]);
            params[l * 256 + 192 + w] = make_float2(E[c], E[c + 16]);
        }
    }
}

// ---------------- CSR build + contention-free counting sort ----------------

__global__ __launch_bounds__(1024) void scan1(const int* __restrict__ deg,
                                              int* __restrict__ rowptr,
                                              int* __restrict__ bsum,
                                              int* __restrict__ blockhist) {
    __shared__ int sd[1024];
    __shared__ int lh[256];
    int t = threadIdx.x;
    int idx = blockIdx.x * 1024 + t;
    if (t < 256) lh[t] = 0;
    __syncthreads();
    int v = (idx < N_NODES) ? deg[idx] : 0;
    if (idx < N_NODES) atomicAdd(&lh[v < 255 ? v : 255], 1);
    sd[t] = v;
    __syncthreads();
    for (int off = 1; off < 1024; off <<= 1) {
        int add = (t >= off) ? sd[t - off] : 0;
        __syncthreads();
        sd[t] += add;
        __syncthreads();
    }
    if (idx < N_NODES) rowptr[idx + 1] = sd[t];
    if (t == 1023) bsum[blockIdx.x] = sd[1023];
    if (t < 256) blockhist[blockIdx.x * 256 + t] = lh[t];
}

__global__ __launch_bounds__(1024) void midscan(const int* __restrict__ bsum,
                                                int* __restrict__ bcarry,
                                                const int* __restrict__ blockhist,
                                                int* __restrict__ bboff) {
    __shared__ int sh[256];
    int t = threadIdx.x;
    if (t < 256) {
        int tot = 0;
        for (int b = 0; b < NSCAN; ++b) tot += blockhist[b * 256 + t];
        sh[t] = tot;
    }
    __syncthreads();
    for (int off = 1; off < 256; off <<= 1) {
        int add = 0;
        if (t < 256 && t >= off) add = sh[t - off];
        __syncthreads();
        if (t < 256) sh[t] += add;
        __syncthreads();
    }
    if (t < 256) {
        int run = sh[255] - sh[t];          // heavy-first
        for (int b = 0; b < NSCAN; ++b) {
            bboff[b * 256 + t] = run;
            run += blockhist[b * 256 + t];
        }
    }
    if (t == 0) {
        int c = 0;
        for (int b = 0; b < NSCAN; ++b) { bcarry[b] = c; c += bsum[b]; }
    }
}

__global__ __launch_bounds__(1024) void scan2(int* __restrict__ rowptr,
                                              const int* __restrict__ bcarry,
                                              const int* __restrict__ deg,
                                              const int* __restrict__ bboff,
                                              int* __restrict__ order) {
    __shared__ int lh[256];
    int t = threadIdx.x;
    int idx = blockIdx.x * 1024 + t;
    if (t < 256) lh[t] = 0;
    __syncthreads();
    int carry = bcarry[blockIdx.x];
    if (idx == 0) rowptr[0] = 0;
    if (idx < N_NODES) {
        rowptr[idx + 1] += carry;
        int d = deg[idx];
        int bin = d < 255 ? d : 255;
        int rank = atomicAdd(&lh[bin], 1);
        order[bboff[blockIdx.x * 256 + bin] + rank] = idx;
    }
}

// ---------------- LDS-staged MFMA GEMM, 64-row tiles, 48KB LDS (+ merged scatter) --
// A (16KB) and B (32KB) staged with full-line linear reads; A-LDS reused for
// output repack; all global stores non-temporal (no dirty L2 -> no boundary flush).

__global__ __launch_bounds__(256) void gemm_sc(
    const ushort* __restrict__ A,      // [N][128] bf16, k-permuted packed order
    const ushort* __restrict__ Wt_l,   // [2][128n][128kperm] bf16
    const float* __restrict__ bl, const float* __restrict__ br,
    unsigned* __restrict__ xlb, unsigned* __restrict__ xrb,
    int do_scat,
    const int* __restrict__ src, const int* __restrict__ dst,
    const int* __restrict__ rowptr, int* __restrict__ cnt,
    int* __restrict__ esrc,
    const int* __restrict__ order, const int* __restrict__ deg,
    int4* __restrict__ slotinfo)
{
    __shared__ char ldsB[32768];
    __shared__ char ldsA[16384];
    int b = blockIdx.x, t = threadIdx.x;
    if (do_scat) {
        if (b < SCATB) {
            int e = b * 256 + t;             // e < 640000 exactly
            int d = dst[e];
            int pos = rowptr[d] + atomicAdd(&cnt[d], 1);
            ntsi(&esrc[pos], src[e] << 8);
            if (e < N_NODES) {
                int nd = order[e];
                int r0 = rowptr[nd];
                ntsi(&slotinfo[e].x, nd);
                ntsi(&slotinfo[e].y, r0);
                ntsi(&slotinfo[e].z, r0 + deg[nd]);
            }
            return;
        }
        b -= SCATB;
    }

    int mat = b & 1;             // adjacent blocks share the A-tile (L3 locality)
    int tile = b >> 1;
    int rowbase = tile * 64;
    const ushort* W = Wt_l + (size_t)mat * DIM * DIM;

    // ---- stage B (32KB) and A (16KB), full-line linear, swizzled chunk placement
    const char* Bb = (const char*)W;
    #pragma unroll
    for (int i = 0; i < 8; ++i) {
        int o = (i * 256 + t) * 16;
        int row = o >> 8, ch = (o >> 4) & 15;
        *(uint4*)&ldsB[row * 256 + ((ch ^ (row & 7)) << 4)] = *(const uint4*)(Bb + o);
    }
    const char* Ab = (const char*)A + (size_t)rowbase * 256;
    #pragma unroll
    for (int i = 0; i < 4; ++i) {
        int o = (i * 256 + t) * 16;
        int row = o >> 8, ch = (o >> 4) & 15;
        *(uint4*)&ldsA[row * 256 + ((ch ^ (row & 7)) << 4)] = *(const uint4*)(Ab + o);
    }
    __syncthreads();

    int wid = t >> 6, lane = t & 63;
    int wr = wid >> 1, wc = wid & 1;     // wave covers 32 rows x 64 cols
    int fr = lane & 15, kg = lane >> 4;

    f32x4 acc[2][4];
    #pragma unroll
    for (int mf = 0; mf < 2; ++mf)
        #pragma unroll
        for (int nf = 0; nf < 4; ++nf)
            acc[mf][nf] = (f32x4){0.f, 0.f, 0.f, 0.f};

    #pragma unroll
    for (int kf = 0; kf < 4; ++kf) {
        int c = kf * 4 + kg;
        bf16x8 af[2], bfr[4];
        #pragma unroll
        for (int mf = 0; mf < 2; ++mf) {
            int rl = wr * 32 + mf * 16 + fr;
            af[mf] = *(const bf16x8*)&ldsA[rl * 256 + ((c ^ (rl & 7)) << 4)];
        }
        #pragma unroll
        for (int nf = 0; nf < 4; ++nf) {
            int nl = wc * 64 + nf * 16 + fr;
            bfr[nf] = *(const bf16x8*)&ldsB[nl * 256 + ((c ^ (nl & 7)) << 4)];
        }
        #pragma unroll
        for (int mf = 0; mf < 2; ++mf)
            #pragma unroll
            for (int nf = 0; nf < 4; ++nf)
                acc[mf][nf] = __builtin_amdgcn_mfma_f32_16x16x32_bf16(
                    af[mf], bfr[nf], acc[mf][nf], 0, 0, 0);
    }
    __syncthreads();    // done reading ldsA -> reuse as output tile

    const float* bias = mat ? br : bl;
    float bb[4];
    #pragma unroll
    for (int nf = 0; nf < 4; ++nf) bb[nf] = bias[wc * 64 + nf * 16 + fr];

    unsigned* ldsO = (unsigned*)ldsA;
    #pragma unroll
    for (int mf = 0; mf < 2; ++mf) {
        #pragma unroll
        for (int pj = 0; pj < 2; ++pj) {
            // channels c = 64*wc + 32*pj + fr, c+16 -> word w = fr + 32*wc + 16*pj
            int w = fr + 32 * wc + 16 * pj;
            #pragma unroll
            for (int r = 0; r < 4; ++r) {
                int rl = wr * 32 + mf * 16 + kg * 4 + r;
                ldsO[rl * 64 + w] =
                    pack2(acc[mf][2 * pj][r] + bb[2 * pj],
                          acc[mf][2 * pj + 1][r] + bb[2 * pj + 1]);
            }
        }
    }
    __syncthreads();

    // ---- coalesced full-line non-temporal output
    unsigned* out = mat ? xrb : xlb;
    char* ob = (char*)out + (size_t)rowbase * 256;
    #pragma unroll
    for (int i = 0; i < 4; ++i) {
        int o = (i * 256 + t) * 16;
        int row = rowbase + (o >> 8);
        if (row < N_NODES)
            nts4(ob + o, *(const uint4v*)&ldsA[o]);
    }
}

// ---------------- fused aggregation (r8 structure + slotinfo + hoisted epilogue) ----

__device__ inline void gather8(const char* __restrict__ xb, int laneoff,
                               const int j[8], unsigned u[8]) {
    #pragma unroll
    for (int i = 0; i < 8; ++i)
        u[i] = *(const unsigned*)(xb + j[i] + laneoff);
}

__device__ inline void compute8(const unsigned u[8], float ax, float ay,
                                float xrx, float xry,
                                float& s, float& ox, float& oy) {
    #pragma unroll
    for (int i = 0; i < 8; ++i) {
        float vx = bf_lo(u[i]), vy = bf_hi(u[i]);
        float p = lr(vx + xrx) * ax + lr(vy + xry) * ay;
        p = reduce16(p);
        float w = EXP2(p);
        s += w; ox = fmaf(w, vx, ox); oy = fmaf(w, vy, oy);
    }
}

__device__ inline void computeT(const unsigned u[8], float ax, float ay,
                                float xrx, float xry,
                                float& s, float& ox, float& oy, int rem) {
    #pragma unroll
    for (int i = 0; i < 8; ++i) {
        if (i < rem) {     // wave-uniform predicate
            float vx = bf_lo(u[i]), vy = bf_hi(u[i]);
            float p = lr(vx + xrx) * ax + lr(vy + xry) * ay;
            p = reduce16(p);
            float w = EXP2(p);
            s += w; ox = fmaf(w, vx, ox); oy = fmaf(w, vy, oy);
        }
    }
}

__global__ __launch_bounds__(256) void agg_kernel(
    const unsigned* __restrict__ xlb2, const unsigned* __restrict__ xrb2,
    const int* __restrict__ esrc, const int4* __restrict__ slotinfo,
    const float2* __restrict__ P4,
    unsigned* __restrict__ curb, float* __restrict__ outf, int last)
{
    int slot = blockIdx.x * 4 + (threadIdx.x >> 6);
    int lane = threadIdx.x & 63;
    int4 si = slotinfo[slot];
    int node = __builtin_amdgcn_readfirstlane(si.x);
    int e0   = __builtin_amdgcn_readfirstlane(si.y);
    int e1   = __builtin_amdgcn_readfirstlane(si.z);

    // hoisted loads: hide their latency under the edge loop
    unsigned xru = xrb2[node * 64 + lane];
    float2 att2 = P4[lane];
    float2 b2   = P4[64 + lane];
    float2 g2   = P4[128 + lane];
    float2 be2  = P4[192 + lane];
    unsigned old = curb[node * 64 + lane];
    float xrx = bf_lo(xru), xry = bf_hi(xru);

    const char* xb = (const char*)xlb2;
    int laneoff = lane << 2;

    float s = 0.f, ox = 0.f, oy = 0.f;
    int nb = (e1 - e0) >> 3;
    int rem = (e1 - e0) & 7;

    int jc[8], jn[8];
    unsigned uc[8], un[8];

    if (nb > 0) {
        #pragma unroll
        for (int i = 0; i < 8; ++i) jc[i] = esrc[e0 + i];   // uniform -> s_load
        gather8(xb, laneoff, jc, uc);
    }
    int ec = e0;
    for (int b = 1; b < nb; ++b) {
        int en = ec + 8;
        #pragma unroll
        for (int i = 0; i < 8; ++i) jn[i] = esrc[en + i];
        gather8(xb, laneoff, jn, un);          // next batch in flight
        compute8(uc, att2.x, att2.y, xrx, xry, s, ox, oy);
        #pragma unroll
        for (int i = 0; i < 8; ++i) uc[i] = un[i];
        ec = en;
    }
    if (nb > 0) {
        if (rem) {
            int et = ec + 8;
            #pragma unroll
            for (int i = 0; i < 8; ++i)
                jn[i] = esrc[et + (i < rem ? i : rem - 1)];
            gather8(xb, laneoff, jn, un);      // tail in flight
            compute8(uc, att2.x, att2.y, xrx, xry, s, ox, oy);
            computeT(un, att2.x, att2.y, xrx, xry, s, ox, oy, rem);
        } else {
            compute8(uc, att2.x, att2.y, xrx, xry, s, ox, oy);
        }
    } else if (rem) {
        #pragma unroll
        for (int i = 0; i < 8; ++i)
            jc[i] = esrc[e0 + (i < rem ? i : rem - 1)];
        gather8(xb, laneoff, jc, uc);
        computeT(uc, att2.x, att2.y, xrx, xry, s, ox, oy, rem);
    }

    float inv = 1.f / (s + 1e-16f);
    float gx = fmaxf(fmaf(ox, inv, b2.x), 0.f);
    float gy = fmaxf(fmaf(oy, inv, b2.y), 0.f);

    // LayerNorm over 128 channels
    float sum = gx + gy;
    sum = reduce16(sum);
    sum += __shfl_xor(sum, 16);
    sum += __shfl_xor(sum, 32);
    float mu = sum * (1.f / 128.f);
    float dx = gx - mu, dy = gy - mu;
    float ss = dx * dx + dy * dy;
    ss = reduce16(ss);
    ss += __shfl_xor(ss, 16);
    ss += __shfl_xor(ss, 32);
    float rstd = rsqrtf(ss * (1.f / 128.f) + LN_EPS);

    float yx = fmaf(dx * rstd, g2.x, be2.x) + bf_lo(old);
    float yy = fmaf(dy * rstd, g2.y, be2.y) + bf_hi(old);

    if (last) {
        int c = cw_of(lane);
        ntsf(&outf[node * DIM + c], yx);
        ntsf(&outf[node * DIM + c + 16], yy);
    } else {
        nts(&curb[node * 64 + lane], pack2(yx, yy));
    }
}

// ---------------- launch ----------------

extern "C" void kernel_launch(void* const* d_in, const int* in_sizes, int n_in,
                              void* d_out, int out_size, void* d_ws, size_t ws_size,
                              hipStream_t stream) {
    const float* x     = (const float*)d_in[0];
    const int*   ei    = (const int*)d_in[1];
    const float* Wl    = (const float*)d_in[2];
    const float* bl    = (const float*)d_in[3];
    const float* Wr    = (const float*)d_in[4];
    const float* br    = (const float*)d_in[5];
    const float* att   = (const float*)d_in[6];
    const float* bias  = (const float*)d_in[7];
    const float* gamma = (const float*)d_in[8];
    const float* beta  = (const float*)d_in[9];
    float* outf = (float*)d_out;

    char* ws = (char*)d_ws;
    size_t off = 0;
    auto alloc = [&](size_t bytes) -> void* {
        void* p = ws + off;
        off += (bytes + 255) & ~size_t(255);
        return p;
    };
    unsigned* curb = (unsigned*)alloc((size_t)N_NODES * 64 * 4);
    unsigned* xlb  = (unsigned*)alloc((size_t)N_NODES * 64 * 4 + 16384);  // +OOB slack
    unsigned* xrb  = (unsigned*)alloc((size_t)N_NODES * 64 * 4 + 16384);
    ushort* Wt     = (ushort*)alloc((size_t)NLAYER * 2 * DIM * DIM * 2);
    int* esrc      = (int*)alloc((size_t)N_EDGES * 4);
    int* rowptr    = (int*)alloc((size_t)(N_NODES + 1) * 4);
    // contiguous zero region: deg, cnt, bsum, bcarry
    int* zbase     = (int*)alloc((size_t)(2 * N_NODES + 2 * 64) * 4);
    int* deg = zbase, *cnt = zbase + N_NODES;
    int* bsum = cnt + N_NODES, *bcarry = bsum + 64;
    int* blockhist = (int*)alloc((size_t)NSCAN * 256 * 4);
    int* bboff     = (int*)alloc((size_t)NSCAN * 256 * 4);
    int* order     = (int*)alloc((size_t)N_NODES * 4);
    int4* slotinfo = (int4*)alloc((size_t)N_NODES * 16);
    float2* params = (float2*)alloc((size_t)NLAYER * 256 * sizeof(float2));

    const int* srcArr = ei;
    const int* dstArr = ei + N_EDGES;

    int n4 = (2 * N_NODES + 2 * 64) / 4;
    zerofill<<<(n4 + 255) / 256, 256, 0, stream>>>((uint4v*)zbase, n4);
    fusedinit<<<15385, 256, 0, stream>>>(x, curb, Wl, Wr, Wt, dstArr, deg,
                                         att, bias, gamma, beta, params);
    scan1<<<NSCAN, 1024, 0, stream>>>(deg, rowptr, bsum, blockhist);
    midscan<<<1, 1024, 0, stream>>>(bsum, bcarry, blockhist, bboff);
    scan2<<<NSCAN, 1024, 0, stream>>>(rowptr, bcarry, deg, bboff, order);

    for (int l = 0; l < NLAYER; ++l) {
        int do_scat = (l == 0) ? 1 : 0;
        int grid = 2 * NT64 + (do_scat ? SCATB : 0);
        gemm_sc<<<grid, 256, 0, stream>>>(
            (const ushort*)curb, Wt + (size_t)l * 2 * DIM * DIM,
            bl + (size_t)l * DIM, br + (size_t)l * DIM, xlb, xrb,
            do_scat, srcArr, dstArr, rowptr, cnt, esrc, order, deg, slotinfo);
        agg_kernel<<<12500, 256, 0, stream>>>(
            xlb, xrb, esrc, slotinfo, params + (size_t)l * 256,
            curb, outf, l == NLAYER - 1 ? 1 : 0);
    }
}

// Round 19
// 232.603 us; speedup vs baseline: 4.5416x; 1.0853x over previous
//
#include <hip/hip_runtime.h>
#include <hip/hip_bf16.h>
#include <math.h>

#define N_NODES 50000
#define N_EDGES 640000
#define DIM 128
#define NLAYER 3
#define LN_EPS 1e-5f
#define LOG2E 1.44269504088896f
#define NSCAN 49    // ceil(50000/1024)
#define NG 391      // ceil(50000/128) 128-row tiles per matrix
#define SCATB 2500  // scatter blocks (640000/256)

#if __has_builtin(__builtin_amdgcn_exp2f)
#define EXP2(x) __builtin_amdgcn_exp2f(x)
#else
#define EXP2(x) exp2f(x)
#endif

typedef __attribute__((ext_vector_type(8))) short bf16x8;
typedef __attribute__((ext_vector_type(4))) float f32x4;

__device__ inline ushort f2b(float f) {
    __hip_bfloat16 h = __float2bfloat16(f);
    return *reinterpret_cast<ushort*>(&h);
}
__device__ inline float bf_lo(unsigned u) { return __uint_as_float(u << 16); }
__device__ inline float bf_hi(unsigned u) { return __uint_as_float(u & 0xffff0000u); }
// leaky_relu(t) = 0.6t + 0.4|t|  (NEG_SLOPE=0.2)
__device__ inline float lr(float t) { return fmaf(0.4f, fabsf(t), 0.6f * t); }
__device__ inline unsigned pack2(float a, float b) {
    return (unsigned)f2b(a) | ((unsigned)f2b(b) << 16);
}
// packed word w of a node row holds channels (cw, cw+16); both in same head.
__device__ inline int cw_of(int w) { return (w & 15) + 32 * (w >> 4); }

// DPP-based add of cross-lane neighbor (VALU, no LDS pipe).
template<int CTRL>
__device__ inline float dppadd(float v) {
    int m = __builtin_amdgcn_update_dpp(0, __float_as_int(v), CTRL, 0xF, 0xF, true);
    return v + __int_as_float(m);
}
// sum over each 16-lane group
__device__ inline float reduce16(float v) {
    v = dppadd<0x124>(v);   // row_ror:4
    v = dppadd<0x128>(v);   // row_ror:8
    v = dppadd<0xB1>(v);    // quad_perm [1,0,3,2]
    v = dppadd<0x4E>(v);    // quad_perm [2,3,0,1]
    return v;
}

// ---------------- zero-fill ----------------

__global__ __launch_bounds__(256) void zerofill(int4* __restrict__ p, int n4) {
    int i = blockIdx.x * 256 + threadIdx.x;
    if (i < n4) p[i] = make_int4(0, 0, 0, 0);
}

// ---------------- fused init: curb pack + Wt convert(k-perm) + deg hist + params ----

__global__ __launch_bounds__(256) void fusedinit(
    const float* __restrict__ x, unsigned* __restrict__ curb,
    const float* __restrict__ Wl, const float* __restrict__ Wr, ushort* __restrict__ Wt,
    const int* __restrict__ dst, int* __restrict__ deg,
    const float* __restrict__ att, const float* __restrict__ bias,
    const float* __restrict__ gamma, const float* __restrict__ beta,
    float2* __restrict__ params)
{
    int b = blockIdx.x, t = threadIdx.x;
    if (b < 12500) {
        int i = b * 256 + t;                 // i < N*64
        int node = i >> 6, w = i & 63;
        int c = cw_of(w);
        curb[i] = pack2(x[node * DIM + c], x[node * DIM + c + 16]);
    } else if (b < 12884) {
        int i = (b - 12500) * 256 + t;
        if (i < NLAYER * 2 * DIM * DIM) {
            int p = i & 127, n = (i >> 7) & 127, mat = (i >> 14) & 1, l = i >> 15;
            int c = cw_of(p >> 1) + (p & 1) * 16;
            const float* W = mat ? Wr : Wl;
            Wt[i] = f2b(W[l * DIM * DIM + c * DIM + n]);
        }
    } else if (b < 15384) {
        int e = (b - 12884) * 256 + t;       // e < 640000 exactly
        atomicAdd(&deg[dst[e]], 1);
    } else {
        int i = t;
        if (i < NLAYER * 64) {
            int l = i >> 6, w = i & 63;
            int c = cw_of(w);
            const float* A = att + l * DIM;
            const float* B = bias + l * DIM;
            const float* G = gamma + l * DIM;
            const float* E = beta + l * DIM;
            params[l * 256 + w]       = make_float2(A[c] * LOG2E, A[c + 16] * LOG2E);
            params[l * 256 + 64 + w]  = make_float2(B[c], B[c + 16]);
            params[l * 256 + 128 + w] = make_float2(G[c], G[c + 16]);
            params[l * 256 + 192 + w] = make_float2(E[c], E[c + 16]);
        }
    }
}

// ---------------- CSR build + contention-free counting sort ----------------

__global__ __launch_bounds__(1024) void scan1(const int* __restrict__ deg,
                                              int* __restrict__ rowptr,
                                              int* __restrict__ bsum,
                                              int* __restrict__ blockhist) {
    __shared__ int sd[1024];
    __shared__ int lh[256];
    int t = threadIdx.x;
    int idx = blockIdx.x * 1024 + t;
    if (t < 256) lh[t] = 0;
    __syncthreads();
    int v = (idx < N_NODES) ? deg[idx] : 0;
    if (idx < N_NODES) atomicAdd(&lh[v < 255 ? v : 255], 1);
    sd[t] = v;
    __syncthreads();
    for (int off = 1; off < 1024; off <<= 1) {
        int add = (t >= off) ? sd[t - off] : 0;
        __syncthreads();
        sd[t] += add;
        __syncthreads();
    }
    if (idx < N_NODES) rowptr[idx + 1] = sd[t];
    if (t == 1023) bsum[blockIdx.x] = sd[1023];
    if (t < 256) blockhist[blockIdx.x * 256 + t] = lh[t];
}

__global__ __launch_bounds__(1024) void midscan(const int* __restrict__ bsum,
                                                int* __restrict__ bcarry,
                                                const int* __restrict__ blockhist,
                                                int* __restrict__ bboff) {
    __shared__ int sh[256];
    int t = threadIdx.x;
    if (t < 256) {
        int tot = 0;
        for (int b = 0; b < NSCAN; ++b) tot += blockhist[b * 256 + t];
        sh[t] = tot;
    }
    __syncthreads();
    for (int off = 1; off < 256; off <<= 1) {
        int add = 0;
        if (t < 256 && t >= off) add = sh[t - off];
        __syncthreads();
        if (t < 256) sh[t] += add;
        __syncthreads();
    }
    if (t < 256) {
        int run = sh[255] - sh[t];          // heavy-first
        for (int b = 0; b < NSCAN; ++b) {
            bboff[b * 256 + t] = run;
            run += blockhist[b * 256 + t];
        }
    }
    if (t == 0) {
        int c = 0;
        for (int b = 0; b < NSCAN; ++b) { bcarry[b] = c; c += bsum[b]; }
    }
}

__global__ __launch_bounds__(1024) void scan2(int* __restrict__ rowptr,
                                              const int* __restrict__ bcarry,
                                              const int* __restrict__ deg,
                                              const int* __restrict__ bboff,
                                              int* __restrict__ order) {
    __shared__ int lh[256];
    int t = threadIdx.x;
    int idx = blockIdx.x * 1024 + t;
    if (t < 256) lh[t] = 0;
    __syncthreads();
    int carry = bcarry[blockIdx.x];
    if (idx == 0) rowptr[0] = 0;
    if (idx < N_NODES) {
        rowptr[idx + 1] += carry;
        int d = deg[idx];
        int bin = d < 255 ? d : 255;
        int rank = atomicAdd(&lh[bin], 1);
        order[bboff[blockIdx.x * 256 + bin] + rank] = idx;
    }
}

// ---------------- LDS-staged MFMA GEMM, 128-row tiles, 64KB LDS (r13 geometry) ----
// A (32KB) and B (32KB) staged with full-line linear reads + chunk-XOR swizzle;
// A-LDS reused for output repack so stores are full-line too. Merged scatter at l=0.

__global__ __launch_bounds__(256) void gemm_sc(
    const ushort* __restrict__ A,      // [N][128] bf16, k-permuted packed order
    const ushort* __restrict__ Wt_l,   // [2][128n][128kperm] bf16
    const float* __restrict__ bl, const float* __restrict__ br,
    unsigned* __restrict__ xlb, unsigned* __restrict__ xrb,
    int do_scat,
    const int* __restrict__ src, const int* __restrict__ dst,
    const int* __restrict__ rowptr, int* __restrict__ cnt,
    int* __restrict__ esrc,
    const int* __restrict__ order, const int* __restrict__ deg,
    int4* __restrict__ slotinfo)
{
    __shared__ char ldsA[32768];
    __shared__ char ldsB[32768];
    int b = blockIdx.x, t = threadIdx.x;
    if (do_scat) {
        if (b < SCATB) {
            int e = b * 256 + t;             // e < 640000 exactly
            int d = dst[e];
            int pos = rowptr[d] + atomicAdd(&cnt[d], 1);
            esrc[pos] = src[e] << 8;
            if (e < N_NODES) {
                int nd = order[e];
                int r0 = rowptr[nd];
                slotinfo[e] = make_int4(nd, r0, r0 + deg[nd], 0);
            }
            return;
        }
        b -= SCATB;
    }

    int mat = b >= NG;
    int rowbase = (mat ? b - NG : b) * 128;

    // ---- stage A-tile (contiguous 32KB) and B-tile, swizzled chunk placement
    const char* Ab = (const char*)A + (size_t)rowbase * 256;
    const char* Bb = (const char*)(Wt_l + (size_t)mat * DIM * DIM);
    #pragma unroll
    for (int i = 0; i < 8; ++i) {
        int o = (i * 256 + t) * 16;              // linear byte offset in tile
        int row = o >> 8, ch = (o >> 4) & 15;
        int sw = row * 256 + ((ch ^ (row & 7)) << 4);
        *(uint4*)&ldsA[sw] = *(const uint4*)(Ab + o);   // coalesced full-line reads
        *(uint4*)&ldsB[sw] = *(const uint4*)(Bb + o);
    }
    __syncthreads();

    int wid = t >> 6, lane = t & 63;
    int wr = wid >> 1, wc = wid & 1;
    int fr = lane & 15, kg = lane >> 4;

    f32x4 acc[4][4];
    #pragma unroll
    for (int mf = 0; mf < 4; ++mf)
        #pragma unroll
        for (int nf = 0; nf < 4; ++nf)
            acc[mf][nf] = (f32x4){0.f, 0.f, 0.f, 0.f};

    #pragma unroll
    for (int kf = 0; kf < 4; ++kf) {
        int c = kf * 4 + kg;
        bf16x8 af[4], bfr[4];
        #pragma unroll
        for (int mf = 0; mf < 4; ++mf) {
            int rl = wr * 64 + mf * 16 + fr;
            af[mf] = *(const bf16x8*)&ldsA[rl * 256 + ((c ^ (rl & 7)) << 4)];
        }
        #pragma unroll
        for (int nf = 0; nf < 4; ++nf) {
            int nl = wc * 64 + nf * 16 + fr;
            bfr[nf] = *(const bf16x8*)&ldsB[nl * 256 + ((c ^ (nl & 7)) << 4)];
        }
        #pragma unroll
        for (int mf = 0; mf < 4; ++mf)
            #pragma unroll
            for (int nf = 0; nf < 4; ++nf)
                acc[mf][nf] = __builtin_amdgcn_mfma_f32_16x16x32_bf16(
                    af[mf], bfr[nf], acc[mf][nf], 0, 0, 0);
    }
    __syncthreads();    // done reading ldsA -> reuse as output tile

    const float* bias = mat ? br : bl;
    int col = fr;
    int r4 = kg;
    float bb[4];
    #pragma unroll
    for (int nf = 0; nf < 4; ++nf) bb[nf] = bias[wc * 64 + nf * 16 + col];

    unsigned* ldsO = (unsigned*)ldsA;
    #pragma unroll
    for (int mf = 0; mf < 4; ++mf) {
        #pragma unroll
        for (int pj = 0; pj < 2; ++pj) {
            // channels c = 64*wc + 32*pj + col, c+16 -> word w = col + 32*wc + 16*pj
            int w = col + 32 * wc + 16 * pj;
            #pragma unroll
            for (int r = 0; r < 4; ++r) {
                int rl = wr * 64 + mf * 16 + r4 * 4 + r;
                ldsO[rl * 64 + w] =
                    pack2(acc[mf][2 * pj][r] + bb[2 * pj],
                          acc[mf][2 * pj + 1][r] + bb[2 * pj + 1]);
            }
        }
    }
    __syncthreads();

    // ---- coalesced full-line output
    unsigned* out = mat ? xrb : xlb;
    char* ob = (char*)out + (size_t)rowbase * 256;
    #pragma unroll
    for (int i = 0; i < 8; ++i) {
        int o = (i * 256 + t) * 16;
        int row = rowbase + (o >> 8);
        if (row < N_NODES)
            *(uint4*)(ob + o) = *(const uint4*)&ldsA[o];
    }
}

// ---------------- fused aggregation (r8 structure + slotinfo + hoisted epilogue) ----

__device__ inline void gather8(const char* __restrict__ xb, int laneoff,
                               const int j[8], unsigned u[8]) {
    #pragma unroll
    for (int i = 0; i < 8; ++i)
        u[i] = *(const unsigned*)(xb + j[i] + laneoff);
}

__device__ inline void compute8(const unsigned u[8], float ax, float ay,
                                float xrx, float xry,
                                float& s, float& ox, float& oy) {
    #pragma unroll
    for (int i = 0; i < 8; ++i) {
        float vx = bf_lo(u[i]), vy = bf_hi(u[i]);
        float p = lr(vx + xrx) * ax + lr(vy + xry) * ay;
        p = reduce16(p);
        float w = EXP2(p);
        s += w; ox = fmaf(w, vx, ox); oy = fmaf(w, vy, oy);
    }
}

__device__ inline void computeT(const unsigned u[8], float ax, float ay,
                                float xrx, float xry,
                                float& s, float& ox, float& oy, int rem) {
    #pragma unroll
    for (int i = 0; i < 8; ++i) {
        if (i < rem) {     // wave-uniform predicate
            float vx = bf_lo(u[i]), vy = bf_hi(u[i]);
            float p = lr(vx + xrx) * ax + lr(vy + xry) * ay;
            p = reduce16(p);
            float w = EXP2(p);
            s += w; ox = fmaf(w, vx, ox); oy = fmaf(w, vy, oy);
        }
    }
}

__global__ __launch_bounds__(256) void agg_kernel(
    const unsigned* __restrict__ xlb2, const unsigned* __restrict__ xrb2,
    const int* __restrict__ esrc, const int4* __restrict__ slotinfo,
    const float2* __restrict__ P4,
    unsigned* __restrict__ curb, float* __restrict__ outf, int last)
{
    int slot = blockIdx.x * 4 + (threadIdx.x >> 6);
    int lane = threadIdx.x & 63;
    int4 si = slotinfo[slot];
    int node = __builtin_amdgcn_readfirstlane(si.x);
    int e0   = __builtin_amdgcn_readfirstlane(si.y);
    int e1   = __builtin_amdgcn_readfirstlane(si.z);

    // hoisted loads: hide their latency under the edge loop
    unsigned xru = xrb2[node * 64 + lane];
    float2 att2 = P4[lane];
    float2 b2   = P4[64 + lane];
    float2 g2   = P4[128 + lane];
    float2 be2  = P4[192 + lane];
    unsigned old = curb[node * 64 + lane];
    float xrx = bf_lo(xru), xry = bf_hi(xru);

    const char* xb = (const char*)xlb2;
    int laneoff = lane << 2;

    float s = 0.f, ox = 0.f, oy = 0.f;
    int nb = (e1 - e0) >> 3;
    int rem = (e1 - e0) & 7;

    int jc[8], jn[8];
    unsigned uc[8], un[8];

    if (nb > 0) {
        #pragma unroll
        for (int i = 0; i < 8; ++i) jc[i] = esrc[e0 + i];   // uniform -> s_load
        gather8(xb, laneoff, jc, uc);
    }
    int ec = e0;
    for (int b = 1; b < nb; ++b) {
        int en = ec + 8;
        #pragma unroll
        for (int i = 0; i < 8; ++i) jn[i] = esrc[en + i];
        gather8(xb, laneoff, jn, un);          // next batch in flight
        compute8(uc, att2.x, att2.y, xrx, xry, s, ox, oy);
        #pragma unroll
        for (int i = 0; i < 8; ++i) uc[i] = un[i];
        ec = en;
    }
    if (nb > 0) {
        if (rem) {
            int et = ec + 8;
            #pragma unroll
            for (int i = 0; i < 8; ++i)
                jn[i] = esrc[et + (i < rem ? i : rem - 1)];
            gather8(xb, laneoff, jn, un);      // tail in flight
            compute8(uc, att2.x, att2.y, xrx, xry, s, ox, oy);
            computeT(un, att2.x, att2.y, xrx, xry, s, ox, oy, rem);
        } else {
            compute8(uc, att2.x, att2.y, xrx, xry, s, ox, oy);
        }
    } else if (rem) {
        #pragma unroll
        for (int i = 0; i < 8; ++i)
            jc[i] = esrc[e0 + (i < rem ? i : rem - 1)];
        gather8(xb, laneoff, jc, uc);
        computeT(uc, att2.x, att2.y, xrx, xry, s, ox, oy, rem);
    }

    float inv = 1.f / (s + 1e-16f);
    float gx = fmaxf(fmaf(ox, inv, b2.x), 0.f);
    float gy = fmaxf(fmaf(oy, inv, b2.y), 0.f);

    // LayerNorm over 128 channels
    float sum = gx + gy;
    sum = reduce16(sum);
    sum += __shfl_xor(sum, 16);
    sum += __shfl_xor(sum, 32);
    float mu = sum * (1.f / 128.f);
    float dx = gx - mu, dy = gy - mu;
    float ss = dx * dx + dy * dy;
    ss = reduce16(ss);
    ss += __shfl_xor(ss, 16);
    ss += __shfl_xor(ss, 32);
    float rstd = rsqrtf(ss * (1.f / 128.f) + LN_EPS);

    float yx = fmaf(dx * rstd, g2.x, be2.x) + bf_lo(old);
    float yy = fmaf(dy * rstd, g2.y, be2.y) + bf_hi(old);

    if (last) {
        int c = cw_of(lane);
        outf[node * DIM + c] = yx;
        outf[node * DIM + c + 16] = yy;
    } else {
        curb[node * 64 + lane] = pack2(yx, yy);
    }
}

// ---------------- launch ----------------

extern "C" void kernel_launch(void* const* d_in, const int* in_sizes, int n_in,
                              void* d_out, int out_size, void* d_ws, size_t ws_size,
                              hipStream_t stream) {
    const float* x     = (const float*)d_in[0];
    const int*   ei    = (const int*)d_in[1];
    const float* Wl    = (const float*)d_in[2];
    const float* bl    = (const float*)d_in[3];
    const float* Wr    = (const float*)d_in[4];
    const float* br    = (const float*)d_in[5];
    const float* att   = (const float*)d_in[6];
    const float* bias  = (const float*)d_in[7];
    const float* gamma = (const float*)d_in[8];
    const float* beta  = (const float*)d_in[9];
    float* outf = (float*)d_out;

    char* ws = (char*)d_ws;
    size_t off = 0;
    auto alloc = [&](size_t bytes) -> void* {
        void* p = ws + off;
        off += (bytes + 255) & ~size_t(255);
        return p;
    };
    unsigned* curb = (unsigned*)alloc((size_t)N_NODES * 64 * 4 + 32768);  // +tile slack
    unsigned* xlb  = (unsigned*)alloc((size_t)N_NODES * 64 * 4 + 32768);
    unsigned* xrb  = (unsigned*)alloc((size_t)N_NODES * 64 * 4 + 32768);
    ushort* Wt     = (ushort*)alloc((size_t)NLAYER * 2 * DIM * DIM * 2);
    int* esrc      = (int*)alloc((size_t)N_EDGES * 4);
    int* rowptr    = (int*)alloc((size_t)(N_NODES + 1) * 4);
    // contiguous zero region: deg, cnt, bsum, bcarry
    int* zbase     = (int*)alloc((size_t)(2 * N_NODES + 2 * 64) * 4);
    int* deg = zbase, *cnt = zbase + N_NODES;
    int* bsum = cnt + N_NODES, *bcarry = bsum + 64;
    int* blockhist = (int*)alloc((size_t)NSCAN * 256 * 4);
    int* bboff     = (int*)alloc((size_t)NSCAN * 256 * 4);
    int* order     = (int*)alloc((size_t)N_NODES * 4);
    int4* slotinfo = (int4*)alloc((size_t)N_NODES * 16);
    float2* params = (float2*)alloc((size_t)NLAYER * 256 * sizeof(float2));

    const int* srcArr = ei;
    const int* dstArr = ei + N_EDGES;

    int n4 = (2 * N_NODES + 2 * 64) / 4;
    zerofill<<<(n4 + 255) / 256, 256, 0, stream>>>((int4*)zbase, n4);
    fusedinit<<<15385, 256, 0, stream>>>(x, curb, Wl, Wr, Wt, dstArr, deg,
                                         att, bias, gamma, beta, params);
    scan1<<<NSCAN, 1024, 0, stream>>>(deg, rowptr, bsum, blockhist);
    midscan<<<1, 1024, 0, stream>>>(bsum, bcarry, blockhist, bboff);
    scan2<<<NSCAN, 1024, 0, stream>>>(rowptr, bcarry, deg, bboff, order);

    for (int l = 0; l < NLAYER; ++l) {
        int do_scat = (l == 0) ? 1 : 0;
        int grid = 2 * NG + (do_scat ? SCATB : 0);
        gemm_sc<<<grid, 256, 0, stream>>>(
            (const ushort*)curb, Wt + (size_t)l * 2 * DIM * DIM,
            bl + (size_t)l * DIM, br + (size_t)l * DIM, xlb, xrb,
            do_scat, srcArr, dstArr, rowptr, cnt, esrc, order, deg, slotinfo);
        agg_kernel<<<12500, 256, 0, stream>>>(
            xlb, xrb, esrc, slotinfo, params + (size_t)l * 256,
            curb, outf, l == NLAYER - 1 ? 1 : 0);
    }
}

// Round 20
// 229.828 us; speedup vs baseline: 4.5964x; 1.0121x over previous
//
#include <hip/hip_runtime.h>
#include <hip/hip_bf16.h>
#include <math.h>

#define N_NODES 50000
#define N_EDGES 640000
#define DIM 128
#define NLAYER 3
#define LN_EPS 1e-5f
#define LOG2E 1.44269504088896f
#define NSCAN 49    // ceil(50000/1024)
#define NG 391      // ceil(50000/128) 128-row tiles per matrix
#define SCATB 2500  // scatter blocks (640000/256)

#if __has_builtin(__builtin_amdgcn_exp2f)
#define EXP2(x) __builtin_amdgcn_exp2f(x)
#else
#define EXP2(x) exp2f(x)
#endif

typedef __attribute__((ext_vector_type(8))) short bf16x8;
typedef __attribute__((ext_vector_type(4))) float f32x4;

__device__ inline ushort f2b(float f) {
    __hip_bfloat16 h = __float2bfloat16(f);
    return *reinterpret_cast<ushort*>(&h);
}
__device__ inline float bf_lo(unsigned u) { return __uint_as_float(u << 16); }
__device__ inline float bf_hi(unsigned u) { return __uint_as_float(u & 0xffff0000u); }
// leaky_relu(t) = 0.6t + 0.4|t|  (NEG_SLOPE=0.2)
__device__ inline float lr(float t) { return fmaf(0.4f, fabsf(t), 0.6f * t); }
__device__ inline unsigned pack2(float a, float b) {
    return (unsigned)f2b(a) | ((unsigned)f2b(b) << 16);
}
// packed word w of a node row holds channels (cw, cw+16); both in same head.
__device__ inline int cw_of(int w) { return (w & 15) + 32 * (w >> 4); }

// DPP-based add of cross-lane neighbor (VALU, no LDS pipe).
template<int CTRL>
__device__ inline float dppadd(float v) {
    int m = __builtin_amdgcn_update_dpp(0, __float_as_int(v), CTRL, 0xF, 0xF, true);
    return v + __int_as_float(m);
}
// sum over each 16-lane group
__device__ inline float reduce16(float v) {
    v = dppadd<0x124>(v);   // row_ror:4
    v = dppadd<0x128>(v);   // row_ror:8
    v = dppadd<0xB1>(v);    // quad_perm [1,0,3,2]
    v = dppadd<0x4E>(v);    // quad_perm [2,3,0,1]
    return v;
}

// ---------------- zero-fill ----------------

__global__ __launch_bounds__(256) void zerofill(int4* __restrict__ p, int n4) {
    int i = blockIdx.x * 256 + threadIdx.x;
    if (i < n4) p[i] = make_int4(0, 0, 0, 0);
}

// ---------------- fused init: curb pack + Wt convert(k-perm) + deg hist + params ----

__global__ __launch_bounds__(256) void fusedinit(
    const float* __restrict__ x, unsigned* __restrict__ curb,
    const float* __restrict__ Wl, const float* __restrict__ Wr, ushort* __restrict__ Wt,
    const int* __restrict__ dst, int* __restrict__ deg,
    const float* __restrict__ att, const float* __restrict__ bias,
    const float* __restrict__ gamma, const float* __restrict__ beta,
    float2* __restrict__ params)
{
    int b = blockIdx.x, t = threadIdx.x;
    if (b < 12500) {
        int i = b * 256 + t;                 // i < N*64
        int node = i >> 6, w = i & 63;
        int c = cw_of(w);
        curb[i] = pack2(x[node * DIM + c], x[node * DIM + c + 16]);
    } else if (b < 12884) {
        int i = (b - 12500) * 256 + t;
        if (i < NLAYER * 2 * DIM * DIM) {
            int p = i & 127, n = (i >> 7) & 127, mat = (i >> 14) & 1, l = i >> 15;
            int c = cw_of(p >> 1) + (p & 1) * 16;
            const float* W = mat ? Wr : Wl;
            Wt[i] = f2b(W[l * DIM * DIM + c * DIM + n]);
        }
    } else if (b < 15384) {
        int e = (b - 12884) * 256 + t;       // e < 640000 exactly
        atomicAdd(&deg[dst[e]], 1);
    } else {
        int i = t;
        if (i < NLAYER * 64) {
            int l = i >> 6, w = i & 63;
            int c = cw_of(w);
            const float* A = att + l * DIM;
            const float* B = bias + l * DIM;
            const float* G = gamma + l * DIM;
            const float* E = beta + l * DIM;
            params[l * 256 + w]       = make_float2(A[c] * LOG2E, A[c + 16] * LOG2E);
            params[l * 256 + 64 + w]  = make_float2(B[c], B[c + 16]);
            params[l * 256 + 128 + w] = make_float2(G[c], G[c + 16]);
            params[l * 256 + 192 + w] = make_float2(E[c], E[c + 16]);
        }
    }
}

// ---------------- CSR build + contention-free counting sort ----------------

__global__ __launch_bounds__(1024) void scan1(const int* __restrict__ deg,
                                              int* __restrict__ rowptr,
                                              int* __restrict__ bsum,
                                              int* __restrict__ blockhist) {
    __shared__ int sd[1024];
    __shared__ int lh[256];
    int t = threadIdx.x;
    int idx = blockIdx.x * 1024 + t;
    if (t < 256) lh[t] = 0;
    __syncthreads();
    int v = (idx < N_NODES) ? deg[idx] : 0;
    if (idx < N_NODES) atomicAdd(&lh[v < 255 ? v : 255], 1);
    sd[t] = v;
    __syncthreads();
    for (int off = 1; off < 1024; off <<= 1) {
        int add = (t >= off) ? sd[t - off] : 0;
        __syncthreads();
        sd[t] += add;
        __syncthreads();
    }
    if (idx < N_NODES) rowptr[idx + 1] = sd[t];
    if (t == 1023) bsum[blockIdx.x] = sd[1023];
    if (t < 256) blockhist[blockIdx.x * 256 + t] = lh[t];
}

__global__ __launch_bounds__(1024) void midscan(const int* __restrict__ bsum,
                                                int* __restrict__ bcarry,
                                                const int* __restrict__ blockhist,
                                                int* __restrict__ bboff) {
    __shared__ int sh[256];
    int t = threadIdx.x;
    if (t < 256) {
        int tot = 0;
        for (int b = 0; b < NSCAN; ++b) tot += blockhist[b * 256 + t];
        sh[t] = tot;
    }
    __syncthreads();
    for (int off = 1; off < 256; off <<= 1) {
        int add = 0;
        if (t < 256 && t >= off) add = sh[t - off];
        __syncthreads();
        if (t < 256) sh[t] += add;
        __syncthreads();
    }
    if (t < 256) {
        int run = sh[255] - sh[t];          // heavy-first
        for (int b = 0; b < NSCAN; ++b) {
            bboff[b * 256 + t] = run;
            run += blockhist[b * 256 + t];
        }
    }
    if (t == 0) {
        int c = 0;
        for (int b = 0; b < NSCAN; ++b) { bcarry[b] = c; c += bsum[b]; }
    }
}

__global__ __launch_bounds__(1024) void scan2(int* __restrict__ rowptr,
                                              const int* __restrict__ bcarry,
                                              const int* __restrict__ deg,
                                              const int* __restrict__ bboff,
                                              int* __restrict__ order) {
    __shared__ int lh[256];
    int t = threadIdx.x;
    int idx = blockIdx.x * 1024 + t;
    if (t < 256) lh[t] = 0;
    __syncthreads();
    int carry = bcarry[blockIdx.x];
    if (idx == 0) rowptr[0] = 0;
    if (idx < N_NODES) {
        rowptr[idx + 1] += carry;
        int d = deg[idx];
        int bin = d < 255 ? d : 255;
        int rank = atomicAdd(&lh[bin], 1);
        order[bboff[blockIdx.x * 256 + bin] + rank] = idx;
    }
}

// ---------------- LDS-staged MFMA GEMM, 128-row tiles, 64KB LDS ----------------
// Staging split into {issue all 16 global loads -> regs} then {LDS writes}: all
// loads in flight before the single vmcnt drain (kills per-iter serialization).

__global__ __launch_bounds__(256) void gemm_sc(
    const ushort* __restrict__ A,      // [N][128] bf16, k-permuted packed order
    const ushort* __restrict__ Wt_l,   // [2][128n][128kperm] bf16
    const float* __restrict__ bl, const float* __restrict__ br,
    unsigned* __restrict__ xlb, unsigned* __restrict__ xrb,
    int do_scat,
    const int* __restrict__ src, const int* __restrict__ dst,
    const int* __restrict__ rowptr, int* __restrict__ cnt,
    int* __restrict__ esrc,
    const int* __restrict__ order, const int* __restrict__ deg,
    int4* __restrict__ slotinfo)
{
    __shared__ char ldsA[32768];
    __shared__ char ldsB[32768];
    int b = blockIdx.x, t = threadIdx.x;
    if (do_scat) {
        if (b < SCATB) {
            int e = b * 256 + t;             // e < 640000 exactly
            int d = dst[e];
            int pos = rowptr[d] + atomicAdd(&cnt[d], 1);
            esrc[pos] = src[e] << 8;
            if (e < N_NODES) {
                int nd = order[e];
                int r0 = rowptr[nd];
                slotinfo[e] = make_int4(nd, r0, r0 + deg[nd], 0);
            }
            return;
        }
        b -= SCATB;
    }

    int mat = b >= NG;
    int rowbase = (mat ? b - NG : b) * 128;

    // ---- stage A-tile (contiguous 32KB) and B-tile: all loads first, then LDS
    const char* Ab = (const char*)A + (size_t)rowbase * 256;
    const char* Bb = (const char*)(Wt_l + (size_t)mat * DIM * DIM);
    uint4 sa[8], sb[8];
    #pragma unroll
    for (int i = 0; i < 8; ++i) {
        int o = (i * 256 + t) * 16;              // linear byte offset in tile
        sa[i] = *(const uint4*)(Ab + o);         // 16 loads in flight
        sb[i] = *(const uint4*)(Bb + o);
    }
    #pragma unroll
    for (int i = 0; i < 8; ++i) {
        int o = (i * 256 + t) * 16;
        int row = o >> 8, ch = (o >> 4) & 15;
        int sw = row * 256 + ((ch ^ (row & 7)) << 4);
        *(uint4*)&ldsA[sw] = sa[i];
        *(uint4*)&ldsB[sw] = sb[i];
    }
    __syncthreads();

    int wid = t >> 6, lane = t & 63;
    int wr = wid >> 1, wc = wid & 1;
    int fr = lane & 15, kg = lane >> 4;

    f32x4 acc[4][4];
    #pragma unroll
    for (int mf = 0; mf < 4; ++mf)
        #pragma unroll
        for (int nf = 0; nf < 4; ++nf)
            acc[mf][nf] = (f32x4){0.f, 0.f, 0.f, 0.f};

    #pragma unroll
    for (int kf = 0; kf < 4; ++kf) {
        int c = kf * 4 + kg;
        bf16x8 af[4], bfr[4];
        #pragma unroll
        for (int mf = 0; mf < 4; ++mf) {
            int rl = wr * 64 + mf * 16 + fr;
            af[mf] = *(const bf16x8*)&ldsA[rl * 256 + ((c ^ (rl & 7)) << 4)];
        }
        #pragma unroll
        for (int nf = 0; nf < 4; ++nf) {
            int nl = wc * 64 + nf * 16 + fr;
            bfr[nf] = *(const bf16x8*)&ldsB[nl * 256 + ((c ^ (nl & 7)) << 4)];
        }
        #pragma unroll
        for (int mf = 0; mf < 4; ++mf)
            #pragma unroll
            for (int nf = 0; nf < 4; ++nf)
                acc[mf][nf] = __builtin_amdgcn_mfma_f32_16x16x32_bf16(
                    af[mf], bfr[nf], acc[mf][nf], 0, 0, 0);
    }
    __syncthreads();    // done reading ldsA -> reuse as output tile

    const float* bias = mat ? br : bl;
    int col = fr;
    int r4 = kg;
    float bb[4];
    #pragma unroll
    for (int nf = 0; nf < 4; ++nf) bb[nf] = bias[wc * 64 + nf * 16 + col];

    unsigned* ldsO = (unsigned*)ldsA;
    #pragma unroll
    for (int mf = 0; mf < 4; ++mf) {
        #pragma unroll
        for (int pj = 0; pj < 2; ++pj) {
            // channels c = 64*wc + 32*pj + col, c+16 -> word w = col + 32*wc + 16*pj
            int w = col + 32 * wc + 16 * pj;
            #pragma unroll
            for (int r = 0; r < 4; ++r) {
                int rl = wr * 64 + mf * 16 + r4 * 4 + r;
                ldsO[rl * 64 + w] =
                    pack2(acc[mf][2 * pj][r] + bb[2 * pj],
                          acc[mf][2 * pj + 1][r] + bb[2 * pj + 1]);
            }
        }
    }
    __syncthreads();

    // ---- coalesced full-line output
    unsigned* out = mat ? xrb : xlb;
    char* ob = (char*)out + (size_t)rowbase * 256;
    #pragma unroll
    for (int i = 0; i < 8; ++i) {
        int o = (i * 256 + t) * 16;
        int row = rowbase + (o >> 8);
        if (row < N_NODES)
            *(uint4*)(ob + o) = *(const uint4*)&ldsA[o];
    }
}

// ---------------- fused aggregation (r8 structure + slotinfo + hoisted epilogue) ----

__device__ inline void gather8(const char* __restrict__ xb, int laneoff,
                               const int j[8], unsigned u[8]) {
    #pragma unroll
    for (int i = 0; i < 8; ++i)
        u[i] = *(const unsigned*)(xb + j[i] + laneoff);
}

__device__ inline void compute8(const unsigned u[8], float ax, float ay,
                                float xrx, float xry,
                                float& s, float& ox, float& oy) {
    #pragma unroll
    for (int i = 0; i < 8; ++i) {
        float vx = bf_lo(u[i]), vy = bf_hi(u[i]);
        float p = lr(vx + xrx) * ax + lr(vy + xry) * ay;
        p = reduce16(p);
        float w = EXP2(p);
        s += w; ox = fmaf(w, vx, ox); oy = fmaf(w, vy, oy);
    }
}

__device__ inline void computeT(const unsigned u[8], float ax, float ay,
                                float xrx, float xry,
                                float& s, float& ox, float& oy, int rem) {
    #pragma unroll
    for (int i = 0; i < 8; ++i) {
        if (i < rem) {     // wave-uniform predicate
            float vx = bf_lo(u[i]), vy = bf_hi(u[i]);
            float p = lr(vx + xrx) * ax + lr(vy + xry) * ay;
            p = reduce16(p);
            float w = EXP2(p);
            s += w; ox = fmaf(w, vx, ox); oy = fmaf(w, vy, oy);
        }
    }
}

__global__ __launch_bounds__(256) void agg_kernel(
    const unsigned* __restrict__ xlb2, const unsigned* __restrict__ xrb2,
    const int* __restrict__ esrc, const int4* __restrict__ slotinfo,
    const float2* __restrict__ P4,
    unsigned* __restrict__ curb, float* __restrict__ outf, int last)
{
    int slot = blockIdx.x * 4 + (threadIdx.x >> 6);
    int lane = threadIdx.x & 63;
    int4 si = slotinfo[slot];
    int node = __builtin_amdgcn_readfirstlane(si.x);
    int e0   = __builtin_amdgcn_readfirstlane(si.y);
    int e1   = __builtin_amdgcn_readfirstlane(si.z);

    // hoisted loads: hide their latency under the edge loop
    unsigned xru = xrb2[node * 64 + lane];
    float2 att2 = P4[lane];
    float2 b2   = P4[64 + lane];
    float2 g2   = P4[128 + lane];
    float2 be2  = P4[192 + lane];
    unsigned old = curb[node * 64 + lane];
    float xrx = bf_lo(xru), xry = bf_hi(xru);

    const char* xb = (const char*)xlb2;
    int laneoff = lane << 2;

    float s = 0.f, ox = 0.f, oy = 0.f;
    int nb = (e1 - e0) >> 3;
    int rem = (e1 - e0) & 7;

    int jc[8], jn[8];
    unsigned uc[8], un[8];

    if (nb > 0) {
        #pragma unroll
        for (int i = 0; i < 8; ++i) jc[i] = esrc[e0 + i];   // uniform -> s_load
        gather8(xb, laneoff, jc, uc);
    }
    int ec = e0;
    for (int b = 1; b < nb; ++b) {
        int en = ec + 8;
        #pragma unroll
        for (int i = 0; i < 8; ++i) jn[i] = esrc[en + i];
        gather8(xb, laneoff, jn, un);          // next batch in flight
        compute8(uc, att2.x, att2.y, xrx, xry, s, ox, oy);
        #pragma unroll
        for (int i = 0; i < 8; ++i) uc[i] = un[i];
        ec = en;
    }
    if (nb > 0) {
        if (rem) {
            int et = ec + 8;
            #pragma unroll
            for (int i = 0; i < 8; ++i)
                jn[i] = esrc[et + (i < rem ? i : rem - 1)];
            gather8(xb, laneoff, jn, un);      // tail in flight
            compute8(uc, att2.x, att2.y, xrx, xry, s, ox, oy);
            computeT(un, att2.x, att2.y, xrx, xry, s, ox, oy, rem);
        } else {
            compute8(uc, att2.x, att2.y, xrx, xry, s, ox, oy);
        }
    } else if (rem) {
        #pragma unroll
        for (int i = 0; i < 8; ++i)
            jc[i] = esrc[e0 + (i < rem ? i : rem - 1)];
        gather8(xb, laneoff, jc, uc);
        computeT(uc, att2.x, att2.y, xrx, xry, s, ox, oy, rem);
    }

    float inv = 1.f / (s + 1e-16f);
    float gx = fmaxf(fmaf(ox, inv, b2.x), 0.f);
    float gy = fmaxf(fmaf(oy, inv, b2.y), 0.f);

    // LayerNorm over 128 channels
    float sum = gx + gy;
    sum = reduce16(sum);
    sum += __shfl_xor(sum, 16);
    sum += __shfl_xor(sum, 32);
    float mu = sum * (1.f / 128.f);
    float dx = gx - mu, dy = gy - mu;
    float ss = dx * dx + dy * dy;
    ss = reduce16(ss);
    ss += __shfl_xor(ss, 16);
    ss += __shfl_xor(ss, 32);
    float rstd = rsqrtf(ss * (1.f / 128.f) + LN_EPS);

    float yx = fmaf(dx * rstd, g2.x, be2.x) + bf_lo(old);
    float yy = fmaf(dy * rstd, g2.y, be2.y) + bf_hi(old);

    if (last) {
        int c = cw_of(lane);
        outf[node * DIM + c] = yx;
        outf[node * DIM + c + 16] = yy;
    } else {
        curb[node * 64 + lane] = pack2(yx, yy);
    }
}

// ---------------- launch ----------------

extern "C" void kernel_launch(void* const* d_in, const int* in_sizes, int n_in,
                              void* d_out, int out_size, void* d_ws, size_t ws_size,
                              hipStream_t stream) {
    const float* x     = (const float*)d_in[0];
    const int*   ei    = (const int*)d_in[1];
    const float* Wl    = (const float*)d_in[2];
    const float* bl    = (const float*)d_in[3];
    const float* Wr    = (const float*)d_in[4];
    const float* br    = (const float*)d_in[5];
    const float* att   = (const float*)d_in[6];
    const float* bias  = (const float*)d_in[7];
    const float* gamma = (const float*)d_in[8];
    const float* beta  = (const float*)d_in[9];
    float* outf = (float*)d_out;

    char* ws = (char*)d_ws;
    size_t off = 0;
    auto alloc = [&](size_t bytes) -> void* {
        void* p = ws + off;
        off += (bytes + 255) & ~size_t(255);
        return p;
    };
    unsigned* curb = (unsigned*)alloc((size_t)N_NODES * 64 * 4 + 32768);  // +tile slack
    unsigned* xlb  = (unsigned*)alloc((size_t)N_NODES * 64 * 4 + 32768);
    unsigned* xrb  = (unsigned*)alloc((size_t)N_NODES * 64 * 4 + 32768);
    ushort* Wt     = (ushort*)alloc((size_t)NLAYER * 2 * DIM * DIM * 2);
    int* esrc      = (int*)alloc((size_t)N_EDGES * 4);
    int* rowptr    = (int*)alloc((size_t)(N_NODES + 1) * 4);
    // contiguous zero region: deg, cnt, bsum, bcarry
    int* zbase     = (int*)alloc((size_t)(2 * N_NODES + 2 * 64) * 4);
    int* deg = zbase, *cnt = zbase + N_NODES;
    int* bsum = cnt + N_NODES, *bcarry = bsum + 64;
    int* blockhist = (int*)alloc((size_t)NSCAN * 256 * 4);
    int* bboff     = (int*)alloc((size_t)NSCAN * 256 * 4);
    int* order     = (int*)alloc((size_t)N_NODES * 4);
    int4* slotinfo = (int4*)alloc((size_t)N_NODES * 16);
    float2* params = (float2*)alloc((size_t)NLAYER * 256 * sizeof(float2));

    const int* srcArr = ei;
    const int* dstArr = ei + N_EDGES;

    int n4 = (2 * N_NODES + 2 * 64) / 4;
    zerofill<<<(n4 + 255) / 256, 256, 0, stream>>>((int4*)zbase, n4);
    fusedinit<<<15385, 256, 0, stream>>>(x, curb, Wl, Wr, Wt, dstArr, deg,
                                         att, bias, gamma, beta, params);
    scan1<<<NSCAN, 1024, 0, stream>>>(deg, rowptr, bsum, blockhist);
    midscan<<<1, 1024, 0, stream>>>(bsum, bcarry, blockhist, bboff);
    scan2<<<NSCAN, 1024, 0, stream>>>(rowptr, bcarry, deg, bboff, order);

    for (int l = 0; l < NLAYER; ++l) {
        int do_scat = (l == 0) ? 1 : 0;
        int grid = 2 * NG + (do_scat ? SCATB : 0);
        gemm_sc<<<grid, 256, 0, stream>>>(
            (const ushort*)curb, Wt + (size_t)l * 2 * DIM * DIM,
            bl + (size_t)l * DIM, br + (size_t)l * DIM, xlb, xrb,
            do_scat, srcArr, dstArr, rowptr, cnt, esrc, order, deg, slotinfo);
        agg_kernel<<<12500, 256, 0, stream>>>(
            xlb, xrb, esrc, slotinfo, params + (size_t)l * 256,
            curb, outf, l == NLAYER - 1 ? 1 : 0);
    }
}